// Round 7
// baseline (337.559 us; speedup 1.0000x reference)
//
#include <hip/hip_runtime.h>
#include <stdint.h>

#define GS   512   // graph size N
#define CF   128   // C_IN = C_OUT
#define XROW 640   // GS + CF
#define NB   128   // batch

typedef __attribute__((ext_vector_type(4))) float          f32x4;
typedef __attribute__((ext_vector_type(8))) short          s16x8;
typedef __attribute__((ext_vector_type(4))) unsigned short u16x4;
typedef __attribute__((ext_vector_type(4))) unsigned int   u32x4;

__device__ __forceinline__ unsigned short f2bf(float f) {
    unsigned u = __builtin_bit_cast(unsigned, f);
    u = (u + 0x7fffu + ((u >> 16) & 1u)) >> 16;   // RNE
    return (unsigned short)u;
}
__device__ __forceinline__ float bf2f(unsigned short h) {
    unsigned u = ((unsigned)h) << 16;
    return __builtin_bit_cast(float, u);
}
__device__ __forceinline__ unsigned cvtpk(float lo, float hi) {   // RNE pack
    unsigned r;
    asm volatile("v_cvt_pk_bf16_f32 %0, %1, %2" : "=v"(r) : "v"(lo), "v"(hi));
    return r;
}
__device__ __forceinline__ s16x8 pack8(f32x4 x0, f32x4 x1) {
    u32x4 p;
    p[0] = cvtpk(x0[0], x0[1]); p[1] = cvtpk(x0[2], x0[3]);
    p[2] = cvtpk(x1[0], x1[1]); p[3] = cvtpk(x1[2], x1[3]);
    return __builtin_bit_cast(s16x8, p);
}
__device__ __forceinline__ void glds16(const void* g, void* l) {
    __builtin_amdgcn_global_load_lds(
        (const __attribute__((address_space(1))) void*)g,
        (__attribute__((address_space(3))) void*)l, 16, 0, 0);
}

// ---------------------------------------------------------------------------
// k0: W (fp32 [c][f]) -> WTst bf16 in fragment-native order:
//     WTst[((ks*4+lk)*128 + f)*8 + j] = bf16(W[ks*32+lk*8+j][f])
// ---------------------------------------------------------------------------
__global__ __launch_bounds__(256) void k0_wt2(const float* __restrict__ W,
                                              unsigned short* __restrict__ WTst) {
    const int e = blockIdx.x * 256 + threadIdx.x;
    const int f = (e >> 3) & 127, q = e >> 10, j = e & 7;
    const int c = (q >> 2) * 32 + (q & 3) * 8 + j;
    WTst[e] = f2bf(W[c * CF + f]);
}

// ---------------------------------------------------------------------------
// kD: pure streaming A-copy + degree. Lane-contiguous float4 (m13 shape),
// NO per-iteration cross-lane: lane partial -> spart[row][lane]; one tail
// reduce -> dis. Reads 134MB, writes 134MB.
// ---------------------------------------------------------------------------
__global__ __launch_bounds__(256) void kD(const float* __restrict__ X,
                                          float* __restrict__ out,
                                          float* __restrict__ dis) {
    __shared__ float spart[64 * 68];                 // stride 68: 16B-aligned rows
    const int t = threadIdx.x, l = t & 63, wv = t >> 6;
    const int m0 = blockIdx.x << 6;
    for (int p = 0; p < 16; ++p) {
        const int rw = (p << 2) + wv, gr = m0 + rw;
        const f32x4* rp = (const f32x4*)(X + (size_t)gr * XROW);
        f32x4* op = (f32x4*)(out + (size_t)gr * XROW);
        f32x4 v0 = rp[l], v1 = rp[l + 64];           // contiguous 1KB per instr
        op[l] = v0; op[l + 64] = v1;
        spart[rw * 68 + l] = (v0[0] + v0[1]) + (v0[2] + v0[3])
                           + (v1[0] + v1[1]) + (v1[2] + v1[3]);
    }
    __syncthreads();
    // tail: 4 threads per row sum 16 partials each, 2 shfl, lane0 writes
    const int r = t >> 2, c = t & 3;
    const float* pr = &spart[r * 68 + (c << 4)];
    f32x4 a0 = *(const f32x4*)pr,       a1 = *(const f32x4*)(pr + 4);
    f32x4 a2 = *(const f32x4*)(pr + 8), a3 = *(const f32x4*)(pr + 12);
    float s = ((a0[0] + a0[1]) + (a0[2] + a0[3])) + ((a1[0] + a1[1]) + (a1[2] + a1[3]))
            + ((a2[0] + a2[1]) + (a2[2] + a2[3])) + ((a3[0] + a3[1]) + (a3[2] + a3[3]));
    s += __shfl_xor(s, 1);
    s += __shfl_xor(s, 2);
    if (c == 0) dis[m0 + r] = (s > 0.f) ? (1.f / sqrtf(s)) : 0.f;
}

// ---------------------------------------------------------------------------
// kPre: fwdT = bf16( dis[m] * (feat[m,:] @ W) ), k3-staging-linear order
//       [b][kt(16)][lk(4)][f(128)][8 m]. LDS-free: A-fragments loaded
//       directly from X fp32 + cvt_pk; W fragments from global (L2 bcast).
// ---------------------------------------------------------------------------
__global__ __launch_bounds__(256) void kPre(const float* __restrict__ X,
                                            const unsigned short* __restrict__ WTst,
                                            const float* __restrict__ dis,
                                            unsigned short* __restrict__ fwdT) {
    const int t = threadIdx.x, l = t & 63, wv = t >> 6;
    const int m0 = blockIdx.x << 6;
    const int b = m0 >> 9, ml0 = m0 & (GS - 1);
    const int wr = wv >> 1, wc = wv & 1, lr = l & 15, lk = l >> 4;

    f32x4 acc[2][4];
#pragma unroll
    for (int i = 0; i < 2; ++i)
#pragma unroll
        for (int j = 0; j < 4; ++j)
#pragma unroll
            for (int r = 0; r < 4; ++r) acc[i][j][r] = 0.f;

#pragma unroll
    for (int ks = 0; ks < 4; ++ks) {
        s16x8 af[2];
#pragma unroll
        for (int i = 0; i < 2; ++i) {
            int row = m0 + (wr << 5) + (i << 4) + lr;
            const float* fp = X + (size_t)row * XROW + GS + (ks << 5) + (lk << 3);
            f32x4 x0 = *(const f32x4*)fp, x1 = *(const f32x4*)(fp + 4);
            af[i] = pack8(x0, x1);
        }
#pragma unroll
        for (int j = 0; j < 4; ++j) {
            int f = (wc << 6) + (j << 4) + lr;
            s16x8 bfr = *(const s16x8*)(WTst + (((((ks << 2) | lk) << 7) | f) << 3));
#pragma unroll
            for (int i = 0; i < 2; ++i)
                acc[i][j] = __builtin_amdgcn_mfma_f32_16x16x32_bf16(af[i], bfr, acc[i][j], 0, 0, 0);
        }
    }

    // epilogue: scale by dis[m], store to fwdT in k3 order
#pragma unroll
    for (int i = 0; i < 2; ++i) {
        int mr = (wr << 5) + (i << 4) + (lk << 2);
        f32x4 d4 = *(const f32x4*)&dis[m0 + mr];
        int mg = ml0 + mr;
        int ktm = mg >> 5, q3 = (mg >> 3) & 3, jm = mg & 7;
#pragma unroll
        for (int j = 0; j < 4; ++j) {
            int f = (wc << 6) + (j << 4) + lr;
            u16x4 o;
            o[0] = f2bf(d4[0] * acc[i][j][0]);
            o[1] = f2bf(d4[1] * acc[i][j][1]);
            o[2] = f2bf(d4[2] * acc[i][j][2]);
            o[3] = f2bf(d4[3] * acc[i][j][3]);
            *(u16x4*)((char*)fwdT + ((size_t)b << 17) + (((ktm << 2) | q3) << 11)
                      + (f << 4) + (jm << 1)) = o;
        }
    }
}

// ---------------------------------------------------------------------------
// k3: out[b,n,512+f] = relu( dis[n] * (A[n,:] @ featWD[:,f] + featWD[n,f]) )
// XCD-swizzled blockIdx (8 blocks of batch b share one XCD's L2 for fwdT).
// A: fp32 directly from X (L3-hot after kD), cvt_pk in-loop, prefetch 1 phase.
// B: double-buffered LDS, BK=64 (2 kt per phase), linear glds16 staging.
// Writes only out[:, 512:640].
// ---------------------------------------------------------------------------
__global__ __launch_bounds__(256) void k3_gcn(const float* __restrict__ X,
                                              const float* __restrict__ dis,
                                              const unsigned short* __restrict__ fwdT,
                                              float* __restrict__ out) {
    __shared__ __align__(16) unsigned short sb[2][8192];    // 16KB per buf
    const int t = threadIdx.x, l = t & 63, wv = t >> 6, lr = l & 15, lk = l >> 4;
    const int ord = blockIdx.x;
    const int L = ((ord & 7) << 7) + (ord >> 3);            // XCD-chunked, bijective
    const int b = L >> 3, bm0 = (L & 7) << 6;
    const char* Bt = (const char*)fwdT + ((size_t)b << 17);
    // lane A source: row = b*512 + bm0 + wv*16 + lr; col base lk*8
    const float* Arow = X + (size_t)(b * GS + bm0 + (wv << 4) + lr) * XROW + (lk << 3);

    auto stage = [&](int buf, int ph) {
#pragma unroll
        for (int it = 0; it < 4; ++it)                       // 16KB = 2 kt-tiles
            glds16(Bt + (ph << 14) + it * 4096 + wv * 1024 + l * 16,
                   (char*)sb[buf] + it * 4096 + wv * 1024);
    };

    f32x4 acc[8];
#pragma unroll
    for (int j = 0; j < 8; ++j)
#pragma unroll
        for (int r = 0; r < 4; ++r) acc[j][r] = 0.f;

    stage(0, 0);
    f32x4 a00 = *(const f32x4*)(Arow),      a01 = *(const f32x4*)(Arow + 4);
    f32x4 a10 = *(const f32x4*)(Arow + 32), a11 = *(const f32x4*)(Arow + 36);
    int cur = 0;
    for (int ph = 0; ph < 8; ++ph) {
        __syncthreads();                                     // drains staging vmcnt
        if (ph < 7) stage(cur ^ 1, ph + 1);
        f32x4 n00 = a00, n01 = a01, n10 = a10, n11 = a11;
        if (ph < 7) {
            const float* nA = Arow + ((2 * ph + 2) << 5);
            n00 = *(const f32x4*)(nA);      n01 = *(const f32x4*)(nA + 4);
            n10 = *(const f32x4*)(nA + 32); n11 = *(const f32x4*)(nA + 36);
        }
        s16x8 a0 = pack8(a00, a01), a1 = pack8(a10, a11);
#pragma unroll
        for (int j = 0; j < 8; ++j) {
            s16x8 bfr = *(const s16x8*)&sb[cur][(lk << 10) + (j << 7) + (lr << 3)];
            acc[j] = __builtin_amdgcn_mfma_f32_16x16x32_bf16(a0, bfr, acc[j], 0, 0, 0);
        }
#pragma unroll
        for (int j = 0; j < 8; ++j) {
            s16x8 bfr = *(const s16x8*)&sb[cur][4096 + (lk << 10) + (j << 7) + (lr << 3)];
            acc[j] = __builtin_amdgcn_mfma_f32_16x16x32_bf16(a1, bfr, acc[j], 0, 0, 0);
        }
        a00 = n00; a01 = n01; a10 = n10; a11 = n11; cur ^= 1;
    }

    // epilogue: + identity featWD[n,f], * dis[n], relu, store fp32
    const int n0r = bm0 + (wv << 4) + (lk << 2);            // base of 4 rows
    f32x4 d4 = *(const f32x4*)&dis[(b << 9) + n0r];
    const int ktm = n0r >> 5, q3 = (n0r >> 3) & 3, jm = n0r & 7;
#pragma unroll
    for (int j = 0; j < 8; ++j) {
        int f = (j << 4) + lr;
        u16x4 fw = *(const u16x4*)(Bt + (((ktm << 2) | q3) << 11) + (f << 4) + (jm << 1));
        float* ob = out + ((size_t)(b * GS + n0r)) * XROW + GS + f;
#pragma unroll
        for (int r = 0; r < 4; ++r) {
            float v = d4[r] * (acc[j][r] + bf2f(fw[r]));
            ob[(size_t)r * XROW] = v > 0.f ? v : 0.f;
        }
    }
}

extern "C" void kernel_launch(void* const* d_in, const int* in_sizes, int n_in,
                              void* d_out, int out_size, void* d_ws, size_t ws_size,
                              hipStream_t stream) {
    const float* X = (const float*)d_in[0];
    const float* W = (const float*)d_in[1];
    float* out = (float*)d_out;
    // ws layout (bytes):
    float*          dis  = (float*)d_ws;                                  // 262144
    unsigned short* WTst = (unsigned short*)((char*)d_ws + 262144);       // 32768
    unsigned short* fwdT = (unsigned short*)((char*)d_ws + 294912);       // 16 MiB

    hipLaunchKernelGGL(k0_wt2, dim3(64),           dim3(256), 0, stream, W, WTst);
    hipLaunchKernelGGL(kD,     dim3(NB * GS / 64), dim3(256), 0, stream, X, out, dis);
    hipLaunchKernelGGL(kPre,   dim3(NB * GS / 64), dim3(256), 0, stream, X, WTst, dis, fwdT);
    hipLaunchKernelGGL(k3_gcn, dim3(NB * GS / 64), dim3(256), 0, stream, X, dis, fwdT, out);
}